// Round 1
// baseline (207.722 us; speedup 1.0000x reference)
//
#include <hip/hip_runtime.h>

#define IN_H  224
#define IN_W  224
#define OUT_H 218
#define OUT_W 218
#define NCH   64
#define KSZ   7

// Each thread: load 8x8 fp32 input patch into registers once, then loop all 64
// output channels (weights are wave-uniform -> SGPR), computing a 2x2 output
// tile per channel. Block = 16x16 threads = 32x32 output pixels.
__global__ __launch_bounds__(256) void conv7x7_kernel(
    const float* __restrict__ in,
    const float* __restrict__ wgt,
    float* __restrict__ out)
{
    const int tx = threadIdx.x & 15;
    const int ty = threadIdx.x >> 4;
    const int n  = blockIdx.z;
    const int X0 = blockIdx.x * 32;
    const int Y0 = blockIdx.y * 32;

    const int ox = X0 + 2 * tx;
    const int oy = Y0 + 2 * ty;
    // Clamp patch origin for fully-out-of-range threads (keeps loads in
    // bounds; their outputs are never stored). Valid threads never clamp:
    // max valid ox = 216 -> patch cols 216..223 = in bounds.
    const int px = min(ox, IN_W - 8);
    const int py = min(oy, IN_H - 8);

    // ---- load 8x8 input patch into registers (float2: px is even) ----
    float p[8][8];
    const float* base = in + (size_t)n * (IN_H * IN_W) + py * IN_W + px;
#pragma unroll
    for (int r = 0; r < 8; ++r) {
        const float2* row = reinterpret_cast<const float2*>(base + r * IN_W);
#pragma unroll
        for (int j = 0; j < 4; ++j) {
            float2 v = row[j];
            p[r][2 * j]     = v.x;
            p[r][2 * j + 1] = v.y;
        }
    }

    // ox,oy even and OUT_W even -> a thread's 2x2 tile is all-valid or
    // all-invalid.
    const bool valid = (ox < OUT_W) && (oy < OUT_H);

    const size_t plane = (size_t)OUT_H * OUT_W;
    float* outbase = out + (size_t)n * NCH * plane;

    for (int c = 0; c < NCH; ++c) {
        const float* w = wgt + c * (KSZ * KSZ);  // wave-uniform -> s_load
        float a00 = 0.f, a01 = 0.f, a10 = 0.f, a11 = 0.f;
#pragma unroll
        for (int r = 0; r < KSZ; ++r) {
#pragma unroll
            for (int s = 0; s < KSZ; ++s) {
                const float wv = w[r * KSZ + s];
                a00 = fmaf(p[r][s],         wv, a00);
                a01 = fmaf(p[r][s + 1],     wv, a01);
                a10 = fmaf(p[r + 1][s],     wv, a10);
                a11 = fmaf(p[r + 1][s + 1], wv, a11);
            }
        }
        if (valid) {
            float* o = outbase + (size_t)c * plane + (size_t)oy * OUT_W + ox;
            *reinterpret_cast<float2*>(o)         = make_float2(a00, a01);
            *reinterpret_cast<float2*>(o + OUT_W) = make_float2(a10, a11);
        }
    }
}

extern "C" void kernel_launch(void* const* d_in, const int* in_sizes, int n_in,
                              void* d_out, int out_size, void* d_ws, size_t ws_size,
                              hipStream_t stream) {
    const float* in  = (const float*)d_in[0];
    const float* wgt = (const float*)d_in[1];
    float* out = (float*)d_out;

    dim3 grid((OUT_W + 31) / 32, (OUT_H + 31) / 32, 32);
    dim3 block(256);
    conv7x7_kernel<<<grid, block, 0, stream>>>(in, wgt, out);
}